// Round 6
// baseline (404.811 us; speedup 1.0000x reference)
//
#include <hip/hip_runtime.h>

// Problem constants
#define BB 4
#define LL 2048
#define DD 1024
#define NH 16
#define DH 64
#define MM (BB*LL)   // 8192 rows

typedef _Float16 half8 __attribute__((ext_vector_type(8)));
typedef _Float16 half4 __attribute__((ext_vector_type(4)));
typedef _Float16 half2 __attribute__((ext_vector_type(2)));
typedef float floatx4 __attribute__((ext_vector_type(4)));

__device__ __forceinline__ void gload_lds16(const void* g, void* l) {
    __builtin_amdgcn_global_load_lds((const __attribute__((address_space(1))) void*)g,
                                     (__attribute__((address_space(3))) void*)l,
                                     16, 0, 0);
}

__device__ __forceinline__ floatx4 mfma16(half8 a, half8 b, floatx4 c) {
    return __builtin_amdgcn_mfma_f32_16x16x32_f16(a, b, c, 0, 0, 0);
}

// ---------------- fused fp32 -> fp16 convert (all 7 tensors, 1 launch) ----------------
__global__ __launch_bounds__(256) void cvt_all(const float* __restrict__ q,
                                               const float* __restrict__ k,
                                               const float* __restrict__ v,
                                               const float* __restrict__ Wq,
                                               const float* __restrict__ Wk,
                                               const float* __restrict__ Wv,
                                               const float* __restrict__ Wo,
                                               _Float16* __restrict__ dst) {
    const int BIG = 8192;
    const int SML = 1024;
    const size_t NQKV = (size_t)MM * DD;
    const size_t NW = (size_t)DD * DD;
    int b = blockIdx.x;
    const float* src;
    size_t off;
    int lb;
    if (b < 3 * BIG) {
        int t = b / BIG;
        src = t == 0 ? q : (t == 1 ? k : v);
        off = (size_t)t * NQKV;
        lb = b - t * BIG;
    } else {
        int t = (b - 3 * BIG) / SML;
        src = t == 0 ? Wq : (t == 1 ? Wk : (t == 2 ? Wv : Wo));
        off = 3 * NQKV + (size_t)t * NW;
        lb = b - 3 * BIG - t * SML;
    }
    size_t i = (size_t)lb * 256 + threadIdx.x;
    float4 f = ((const float4*)src)[i];
    half4 h;
    h[0] = (_Float16)f.x; h[1] = (_Float16)f.y;
    h[2] = (_Float16)f.z; h[3] = (_Float16)f.w;
    ((half4*)(dst + off))[i] = h;
}

// ---------------- fused QKV projection GEMM ----------------
// grid (24, 64): bx 0..7 -> Q (+l2norm), 8..15 -> K (+l2norm), 16..23 -> V (transposed store)
__global__ __launch_bounds__(256) void gemm_qkv(const _Float16* __restrict__ qkv16,
                                                const _Float16* __restrict__ wq,
                                                const _Float16* __restrict__ wk,
                                                const _Float16* __restrict__ wv,
                                                const float* __restrict__ bq,
                                                const float* __restrict__ bk,
                                                const float* __restrict__ bv,
                                                _Float16* __restrict__ Qp,
                                                _Float16* __restrict__ Kp,
                                                _Float16* __restrict__ VtG) {
    const int K = 1024;
    __shared__ _Float16 As[128 * 32];
    __shared__ _Float16 Bs[128 * 32];

    int tid = threadIdx.x;
    int wave = tid >> 6, lane = tid & 63;
    int quad = lane >> 4, l15 = lane & 15;
    int wrow = (wave >> 1) * 64, wcol = (wave & 1) * 64;
    int bx = blockIdx.x;
    int which = bx >> 3;  // 0=Q, 1=K, 2=V
    int m0 = blockIdx.y * 128;
    int n0 = (bx & 7) * 128;

    const _Float16* A = qkv16 + (size_t)which * ((size_t)MM * DD);
    const _Float16* W = which == 0 ? wq : (which == 1 ? wk : wv);
    const float* bias = which == 0 ? bq : (which == 1 ? bk : bv);

    floatx4 acc[4][4] = {};

    int srow = tid >> 2, sseg = tid & 3;
    const _Float16* Ag0 = A + (size_t)(m0 + srow) * K + sseg * 8;
    const _Float16* Ag1 = Ag0 + (size_t)64 * K;
    const _Float16* Bg0 = W + (size_t)(n0 + srow) * K + sseg * 8;
    const _Float16* Bg1 = Bg0 + (size_t)64 * K;
    char* ldsA0 = (char*)As + tid * 16;
    char* ldsA1 = (char*)As + (256 + tid) * 16;
    char* ldsB0 = (char*)Bs + tid * 16;
    char* ldsB1 = (char*)Bs + (256 + tid) * 16;

    for (int kt = 0; kt < K; kt += 32) {
        __syncthreads();
        gload_lds16(Ag0 + kt, ldsA0);
        gload_lds16(Ag1 + kt, ldsA1);
        gload_lds16(Bg0 + kt, ldsB0);
        gload_lds16(Bg1 + kt, ldsB1);
        __syncthreads();

        half8 af[4], bf[4];
#pragma unroll
        for (int i = 0; i < 4; i++)
            af[i] = *(half8*)&As[(wrow + i * 16 + l15) * 32 + quad * 8];
#pragma unroll
        for (int j = 0; j < 4; j++)
            bf[j] = *(half8*)&Bs[(wcol + j * 16 + l15) * 32 + quad * 8];
#pragma unroll
        for (int i = 0; i < 4; i++)
#pragma unroll
            for (int j = 0; j < 4; j++)
                acc[i][j] = mfma16(af[i], bf[j], acc[i][j]);
    }

#pragma unroll
    for (int j = 0; j < 4; j++) {
        float bv_ = bias[n0 + wcol + j * 16 + l15];
#pragma unroll
        for (int i = 0; i < 4; i++)
#pragma unroll
            for (int r = 0; r < 4; r++) acc[i][j][r] += bv_;
    }

    if (which < 2) {
        _Float16* C = which == 0 ? Qp : Kp;
#pragma unroll
        for (int i = 0; i < 4; i++) {
#pragma unroll
            for (int r = 0; r < 4; r++) {
                float s = 0.f;
#pragma unroll
                for (int j = 0; j < 4; j++) s += acc[i][j][r] * acc[i][j][r];
                s += __shfl_xor(s, 1);
                s += __shfl_xor(s, 2);
                s += __shfl_xor(s, 4);
                s += __shfl_xor(s, 8);
                float inv = 1.0f / fmaxf(sqrtf(s), 1e-12f);
                int row = m0 + wrow + i * 16 + quad * 4 + r;
#pragma unroll
                for (int j = 0; j < 4; j++) {
                    int col = n0 + wcol + j * 16 + l15;
                    C[(size_t)row * DD + col] = (_Float16)(acc[i][j][r] * inv);
                }
            }
        }
    } else {
#pragma unroll
        for (int j = 0; j < 4; j++) {
            int col = n0 + wcol + j * 16 + l15;  // h*64+dh
#pragma unroll
            for (int i = 0; i < 4; i++) {
#pragma unroll
                for (int r = 0; r < 4; r++) {
                    int row = m0 + wrow + i * 16 + quad * 4 + r;  // b*2048 + l
                    int b = row >> 11, l = row & 2047;
                    VtG[((size_t)((b << 10) + col)) * LL + l] = (_Float16)acc[i][j][r];
                }
            }
        }
    }
}

// ---------------- output projection GEMM (fp32 out) ----------------
__global__ __launch_bounds__(256) void gemm_out(const _Float16* __restrict__ A,
                                                const _Float16* __restrict__ W,
                                                const float* __restrict__ bias,
                                                float* __restrict__ C) {
    const int K = 1024, N = 1024;
    __shared__ _Float16 As[128 * 32];
    __shared__ _Float16 Bs[128 * 32];

    int tid = threadIdx.x;
    int wave = tid >> 6, lane = tid & 63;
    int quad = lane >> 4, l15 = lane & 15;
    int wrow = (wave >> 1) * 64, wcol = (wave & 1) * 64;
    int m0 = blockIdx.y * 128;
    int n0 = blockIdx.x * 128;

    floatx4 acc[4][4] = {};

    int srow = tid >> 2, sseg = tid & 3;
    const _Float16* Ag0 = A + (size_t)(m0 + srow) * K + sseg * 8;
    const _Float16* Ag1 = Ag0 + (size_t)64 * K;
    const _Float16* Bg0 = W + (size_t)(n0 + srow) * K + sseg * 8;
    const _Float16* Bg1 = Bg0 + (size_t)64 * K;
    char* ldsA0 = (char*)As + tid * 16;
    char* ldsA1 = (char*)As + (256 + tid) * 16;
    char* ldsB0 = (char*)Bs + tid * 16;
    char* ldsB1 = (char*)Bs + (256 + tid) * 16;

    for (int kt = 0; kt < K; kt += 32) {
        __syncthreads();
        gload_lds16(Ag0 + kt, ldsA0);
        gload_lds16(Ag1 + kt, ldsA1);
        gload_lds16(Bg0 + kt, ldsB0);
        gload_lds16(Bg1 + kt, ldsB1);
        __syncthreads();

        half8 af[4], bf[4];
#pragma unroll
        for (int i = 0; i < 4; i++)
            af[i] = *(half8*)&As[(wrow + i * 16 + l15) * 32 + quad * 8];
#pragma unroll
        for (int j = 0; j < 4; j++)
            bf[j] = *(half8*)&Bs[(wcol + j * 16 + l15) * 32 + quad * 8];
#pragma unroll
        for (int i = 0; i < 4; i++)
#pragma unroll
            for (int j = 0; j < 4; j++)
                acc[i][j] = mfma16(af[i], bf[j], acc[i][j]);
    }

#pragma unroll
    for (int j = 0; j < 4; j++) {
        int col = n0 + wcol + j * 16 + l15;
        float bv = bias[col];
#pragma unroll
        for (int i = 0; i < 4; i++) {
#pragma unroll
            for (int r = 0; r < 4; r++) {
                int row = m0 + wrow + i * 16 + quad * 4 + r;
                C[(size_t)row * N + col] = acc[i][j][r] + bv;
            }
        }
    }
}

// ---------------- fused cosine attention v3: 256-query blocks ----------------
// grid: (L/256, B*H). 256 thr = 4 waves; wave w owns queries w*64..w*64+63 (ib=4).
// kf/vf fragment reads amortized over 2x queries vs v2; K/V staging per unit work halved.
__global__ __launch_bounds__(256) void attn_k(const _Float16* __restrict__ Q,
                                              const _Float16* __restrict__ K,
                                              const _Float16* __restrict__ VtG,
                                              _Float16* __restrict__ Mg) {
    __shared__ _Float16 Ks[64 * 64];   // 8 KB
    __shared__ _Float16 Vt[64 * 64];   // 8 KB
    __shared__ _Float16 Ps[256 * 64];  // 32 KB
    __shared__ float lsum[256];

    const float C2 = 20.60992915555662f;  // log2(e)/0.07
    const float OFF = 6.0f;

    int tid = threadIdx.x, wave = tid >> 6, lane = tid & 63;
    int quad = lane >> 4, l15 = lane & 15;
    int bh = blockIdx.y;
    int b = bh >> 4, h = bh & 15;
    int q0 = blockIdx.x * 256;
    size_t rowBase = (size_t)b * LL;
    int colBase = h * 64;
    int wq = wave * 64;
    int sw = l15 & 7;

    // Q fragments in registers for the whole kernel: 4 ib x 2 ks
    half8 qf[4][2];
#pragma unroll
    for (int ib = 0; ib < 4; ib++)
#pragma unroll
        for (int ks = 0; ks < 2; ks++)
            qf[ib][ks] = *(const half8*)(Q + (rowBase + q0 + wq + ib * 16 + l15) * DD +
                                         colBase + ks * 32 + quad * 8);

    const _Float16* kg[2];
    const _Float16* vg[2];
    char* kl[2];
    char* vl[2];
#pragma unroll
    for (int p = 0; p < 2; p++) {
        int s = p * 256 + tid;
        int r = s >> 3, cs = s & 7;
        int ck = cs ^ (r & 7);
        kg[p] = K + (rowBase + r) * DD + colBase + ck * 8;
        kl[p] = (char*)Ks + s * 16;
        vg[p] = VtG + ((size_t)bh * 64 + r) * LL + ck * 8;
        vl[p] = (char*)Vt + s * 16;
    }

    floatx4 oacc[4][4] = {};
    float fsum[4] = {0.f, 0.f, 0.f, 0.f};

    for (int kt = 0; kt < LL; kt += 64) {
        __syncthreads();
        gload_lds16(kg[0], kl[0]); kg[0] += 64 * DD;
        gload_lds16(kg[1], kl[1]); kg[1] += 64 * DD;
        gload_lds16(vg[0], vl[0]); vg[0] += 64;
        gload_lds16(vg[1], vl[1]); vg[1] += 64;
        __syncthreads();

        // ---- S^T = K * Q^T : D[key][q], 64 keys x 64 queries per wave ----
        floatx4 st[4][4] = {};  // [ib][jb(key block)]
#pragma unroll
        for (int ks = 0; ks < 2; ks++) {
            half8 kf[4];
#pragma unroll
            for (int jb = 0; jb < 4; jb++)
                kf[jb] = *(half8*)&Ks[(jb * 16 + l15) * 64 + (((ks * 4 + quad) ^ sw) * 8)];
#pragma unroll
            for (int ib = 0; ib < 4; ib++)
#pragma unroll
                for (int jb = 0; jb < 4; jb++)
                    st[ib][jb] = mfma16(kf[jb], qf[ib][ks], st[ib][jb]);
        }

        // ---- P = exp2(s*C2-OFF), pack -> b64 LDS writes (wave-exclusive rows) ----
#pragma unroll
        for (int ib = 0; ib < 4; ib++) {
#pragma unroll
            for (int jb = 0; jb < 4; jb++) {
                float e0 = __builtin_amdgcn_exp2f(st[ib][jb][0] * C2 - OFF);
                float e1 = __builtin_amdgcn_exp2f(st[ib][jb][1] * C2 - OFF);
                float e2 = __builtin_amdgcn_exp2f(st[ib][jb][2] * C2 - OFF);
                float e3 = __builtin_amdgcn_exp2f(st[ib][jb][3] * C2 - OFF);
                fsum[ib] += (e0 + e1) + (e2 + e3);
                half2 p01 = __builtin_bit_cast(half2, __builtin_amdgcn_cvt_pkrtz(e0, e1));
                half2 p23 = __builtin_bit_cast(half2, __builtin_amdgcn_cvt_pkrtz(e2, e3));
                half4 pk; pk[0] = p01[0]; pk[1] = p01[1]; pk[2] = p23[0]; pk[3] = p23[1];
                int chunk = (jb * 2 + (quad >> 1)) ^ sw;
                *(half4*)((char*)Ps + (wq + ib * 16 + l15) * 128 + chunk * 16 + (quad & 1) * 8) = pk;
            }
        }

        // ---- O += P * V^T-frags ----
#pragma unroll
        for (int kb = 0; kb < 2; kb++) {
            half8 pf[4], vf[4];
#pragma unroll
            for (int ib = 0; ib < 4; ib++)
                pf[ib] = *(half8*)&Ps[(wq + ib * 16 + l15) * 64 + (((kb * 4 + quad) ^ sw) * 8)];
#pragma unroll
            for (int jb = 0; jb < 4; jb++)
                vf[jb] = *(half8*)&Vt[(jb * 16 + l15) * 64 + (((kb * 4 + quad) ^ sw) * 8)];
#pragma unroll
            for (int ib = 0; ib < 4; ib++)
#pragma unroll
                for (int jb = 0; jb < 4; jb++)
                    oacc[ib][jb] = mfma16(pf[ib], vf[jb], oacc[ib][jb]);
        }
    }

    // ---- epilogue ----
#pragma unroll
    for (int ib = 0; ib < 4; ib++) {
        float v = fsum[ib];
        v += __shfl_xor(v, 16);
        v += __shfl_xor(v, 32);
        lsum[wq + ib * 16 + l15] = v;
    }
#pragma unroll
    for (int ib = 0; ib < 4; ib++) {
#pragma unroll
        for (int r = 0; r < 4; r++) {
            float inv = 1.0f / lsum[wq + ib * 16 + quad * 4 + r];
            int qrow = q0 + wq + ib * 16 + quad * 4 + r;
#pragma unroll
            for (int jb = 0; jb < 4; jb++) {
                float v = oacc[ib][jb][r] * inv;
                Mg[(rowBase + qrow) * DD + colBase + jb * 16 + l15] = (_Float16)v;
            }
        }
    }
}

// ---------------- launch ----------------
extern "C" void kernel_launch(void* const* d_in, const int* in_sizes, int n_in,
                              void* d_out, int out_size, void* d_ws, size_t ws_size,
                              hipStream_t stream) {
    (void)in_sizes; (void)n_in; (void)out_size; (void)ws_size;
    const float* q  = (const float*)d_in[0];
    const float* k  = (const float*)d_in[1];
    const float* v  = (const float*)d_in[2];
    const float* Wq = (const float*)d_in[3];
    const float* bq = (const float*)d_in[4];
    const float* Wk = (const float*)d_in[5];
    const float* bk = (const float*)d_in[6];
    const float* Wv = (const float*)d_in[7];
    const float* bv = (const float*)d_in[8];
    const float* Wo = (const float*)d_in[9];
    const float* bo = (const float*)d_in[10];

    const size_t NQKV = (size_t)MM * DD;  // 8388608
    const size_t NW = (size_t)DD * DD;    // 1048576

    _Float16* q16  = (_Float16*)d_ws;
    _Float16* wq16 = q16 + 3 * NQKV;
    _Float16* wk16 = wq16 + NW;
    _Float16* wv16 = wk16 + NW;
    _Float16* wo16 = wv16 + NW;
    _Float16* Qp   = wo16 + NW;
    _Float16* Kp   = Qp + NQKV;
    _Float16* VtG  = Kp + NQKV;
    _Float16* Mg   = VtG + NQKV;

    cvt_all<<<dim3(3 * 8192 + 4 * 1024), dim3(256), 0, stream>>>(q, k, v, Wq, Wk, Wv, Wo, q16);

    gemm_qkv<<<dim3(24, MM / 128), dim3(256), 0, stream>>>(q16, wq16, wk16, wv16,
                                                           bq, bk, bv, Qp, Kp, VtG);

    attn_k<<<dim3(LL / 256, BB * NH), dim3(256), 0, stream>>>(Qp, Kp, VtG, Mg);

    gemm_out<<<dim3(1024 / 128, MM / 128), dim3(256), 0, stream>>>(Mg, wo16, bo, (float*)d_out);
}

// Round 7
// 404.049 us; speedup vs baseline: 1.0019x; 1.0019x over previous
//
#include <hip/hip_runtime.h>

// Problem constants
#define BB 4
#define LL 2048
#define DD 1024
#define NH 16
#define DH 64
#define MM (BB*LL)   // 8192 rows

typedef _Float16 half8 __attribute__((ext_vector_type(8)));
typedef _Float16 half4 __attribute__((ext_vector_type(4)));
typedef _Float16 half2 __attribute__((ext_vector_type(2)));
typedef float floatx4 __attribute__((ext_vector_type(4)));

__device__ __forceinline__ void gload_lds16(const void* g, void* l) {
    __builtin_amdgcn_global_load_lds((const __attribute__((address_space(1))) void*)g,
                                     (__attribute__((address_space(3))) void*)l,
                                     16, 0, 0);
}

__device__ __forceinline__ floatx4 mfma16(half8 a, half8 b, floatx4 c) {
    return __builtin_amdgcn_mfma_f32_16x16x32_f16(a, b, c, 0, 0, 0);
}

// ---------------- fused fp32 -> fp16 convert (all 7 tensors, 1 launch) ----------------
__global__ __launch_bounds__(256) void cvt_all(const float* __restrict__ q,
                                               const float* __restrict__ k,
                                               const float* __restrict__ v,
                                               const float* __restrict__ Wq,
                                               const float* __restrict__ Wk,
                                               const float* __restrict__ Wv,
                                               const float* __restrict__ Wo,
                                               _Float16* __restrict__ dst) {
    const int BIG = 8192;
    const int SML = 1024;
    const size_t NQKV = (size_t)MM * DD;
    const size_t NW = (size_t)DD * DD;
    int b = blockIdx.x;
    const float* src;
    size_t off;
    int lb;
    if (b < 3 * BIG) {
        int t = b / BIG;
        src = t == 0 ? q : (t == 1 ? k : v);
        off = (size_t)t * NQKV;
        lb = b - t * BIG;
    } else {
        int t = (b - 3 * BIG) / SML;
        src = t == 0 ? Wq : (t == 1 ? Wk : (t == 2 ? Wv : Wo));
        off = 3 * NQKV + (size_t)t * NW;
        lb = b - 3 * BIG - t * SML;
    }
    size_t i = (size_t)lb * 256 + threadIdx.x;
    float4 f = ((const float4*)src)[i];
    half4 h;
    h[0] = (_Float16)f.x; h[1] = (_Float16)f.y;
    h[2] = (_Float16)f.z; h[3] = (_Float16)f.w;
    ((half4*)(dst + off))[i] = h;
}

// ---------------- fused QKV projection GEMM ----------------
// grid (24, 64): bx 0..7 -> Q (+l2norm), 8..15 -> K (+l2norm), 16..23 -> V (transposed store)
__global__ __launch_bounds__(256) void gemm_qkv(const _Float16* __restrict__ qkv16,
                                                const _Float16* __restrict__ wq,
                                                const _Float16* __restrict__ wk,
                                                const _Float16* __restrict__ wv,
                                                const float* __restrict__ bq,
                                                const float* __restrict__ bk,
                                                const float* __restrict__ bv,
                                                _Float16* __restrict__ Qp,
                                                _Float16* __restrict__ Kp,
                                                _Float16* __restrict__ VtG) {
    const int K = 1024;
    __shared__ _Float16 As[128 * 32];
    __shared__ _Float16 Bs[128 * 32];

    int tid = threadIdx.x;
    int wave = tid >> 6, lane = tid & 63;
    int quad = lane >> 4, l15 = lane & 15;
    int wrow = (wave >> 1) * 64, wcol = (wave & 1) * 64;
    int bx = blockIdx.x;
    int which = bx >> 3;  // 0=Q, 1=K, 2=V
    int m0 = blockIdx.y * 128;
    int n0 = (bx & 7) * 128;

    const _Float16* A = qkv16 + (size_t)which * ((size_t)MM * DD);
    const _Float16* W = which == 0 ? wq : (which == 1 ? wk : wv);
    const float* bias = which == 0 ? bq : (which == 1 ? bk : bv);

    floatx4 acc[4][4] = {};

    int srow = tid >> 2, sseg = tid & 3;
    const _Float16* Ag0 = A + (size_t)(m0 + srow) * K + sseg * 8;
    const _Float16* Ag1 = Ag0 + (size_t)64 * K;
    const _Float16* Bg0 = W + (size_t)(n0 + srow) * K + sseg * 8;
    const _Float16* Bg1 = Bg0 + (size_t)64 * K;
    char* ldsA0 = (char*)As + tid * 16;
    char* ldsA1 = (char*)As + (256 + tid) * 16;
    char* ldsB0 = (char*)Bs + tid * 16;
    char* ldsB1 = (char*)Bs + (256 + tid) * 16;

    for (int kt = 0; kt < K; kt += 32) {
        __syncthreads();
        gload_lds16(Ag0 + kt, ldsA0);
        gload_lds16(Ag1 + kt, ldsA1);
        gload_lds16(Bg0 + kt, ldsB0);
        gload_lds16(Bg1 + kt, ldsB1);
        __syncthreads();

        half8 af[4], bf[4];
#pragma unroll
        for (int i = 0; i < 4; i++)
            af[i] = *(half8*)&As[(wrow + i * 16 + l15) * 32 + quad * 8];
#pragma unroll
        for (int j = 0; j < 4; j++)
            bf[j] = *(half8*)&Bs[(wcol + j * 16 + l15) * 32 + quad * 8];
#pragma unroll
        for (int i = 0; i < 4; i++)
#pragma unroll
            for (int j = 0; j < 4; j++)
                acc[i][j] = mfma16(af[i], bf[j], acc[i][j]);
    }

#pragma unroll
    for (int j = 0; j < 4; j++) {
        float bv_ = bias[n0 + wcol + j * 16 + l15];
#pragma unroll
        for (int i = 0; i < 4; i++)
#pragma unroll
            for (int r = 0; r < 4; r++) acc[i][j][r] += bv_;
    }

    if (which < 2) {
        _Float16* C = which == 0 ? Qp : Kp;
#pragma unroll
        for (int i = 0; i < 4; i++) {
#pragma unroll
            for (int r = 0; r < 4; r++) {
                float s = 0.f;
#pragma unroll
                for (int j = 0; j < 4; j++) s += acc[i][j][r] * acc[i][j][r];
                s += __shfl_xor(s, 1);
                s += __shfl_xor(s, 2);
                s += __shfl_xor(s, 4);
                s += __shfl_xor(s, 8);
                float inv = 1.0f / fmaxf(sqrtf(s), 1e-12f);
                int row = m0 + wrow + i * 16 + quad * 4 + r;
#pragma unroll
                for (int j = 0; j < 4; j++) {
                    int col = n0 + wcol + j * 16 + l15;
                    C[(size_t)row * DD + col] = (_Float16)(acc[i][j][r] * inv);
                }
            }
        }
    } else {
#pragma unroll
        for (int j = 0; j < 4; j++) {
            int col = n0 + wcol + j * 16 + l15;  // h*64+dh
#pragma unroll
            for (int i = 0; i < 4; i++) {
#pragma unroll
                for (int r = 0; r < 4; r++) {
                    int row = m0 + wrow + i * 16 + quad * 4 + r;  // b*2048 + l
                    int b = row >> 11, l = row & 2047;
                    VtG[((size_t)((b << 10) + col)) * LL + l] = (_Float16)acc[i][j][r];
                }
            }
        }
    }
}

// ---------------- output projection GEMM (fp32 out) ----------------
__global__ __launch_bounds__(256) void gemm_out(const _Float16* __restrict__ A,
                                                const _Float16* __restrict__ W,
                                                const float* __restrict__ bias,
                                                float* __restrict__ C) {
    const int K = 1024, N = 1024;
    __shared__ _Float16 As[128 * 32];
    __shared__ _Float16 Bs[128 * 32];

    int tid = threadIdx.x;
    int wave = tid >> 6, lane = tid & 63;
    int quad = lane >> 4, l15 = lane & 15;
    int wrow = (wave >> 1) * 64, wcol = (wave & 1) * 64;
    int m0 = blockIdx.y * 128;
    int n0 = blockIdx.x * 128;

    floatx4 acc[4][4] = {};

    int srow = tid >> 2, sseg = tid & 3;
    const _Float16* Ag0 = A + (size_t)(m0 + srow) * K + sseg * 8;
    const _Float16* Ag1 = Ag0 + (size_t)64 * K;
    const _Float16* Bg0 = W + (size_t)(n0 + srow) * K + sseg * 8;
    const _Float16* Bg1 = Bg0 + (size_t)64 * K;
    char* ldsA0 = (char*)As + tid * 16;
    char* ldsA1 = (char*)As + (256 + tid) * 16;
    char* ldsB0 = (char*)Bs + tid * 16;
    char* ldsB1 = (char*)Bs + (256 + tid) * 16;

    for (int kt = 0; kt < K; kt += 32) {
        __syncthreads();
        gload_lds16(Ag0 + kt, ldsA0);
        gload_lds16(Ag1 + kt, ldsA1);
        gload_lds16(Bg0 + kt, ldsB0);
        gload_lds16(Bg1 + kt, ldsB1);
        __syncthreads();

        half8 af[4], bf[4];
#pragma unroll
        for (int i = 0; i < 4; i++)
            af[i] = *(half8*)&As[(wrow + i * 16 + l15) * 32 + quad * 8];
#pragma unroll
        for (int j = 0; j < 4; j++)
            bf[j] = *(half8*)&Bs[(wcol + j * 16 + l15) * 32 + quad * 8];
#pragma unroll
        for (int i = 0; i < 4; i++)
#pragma unroll
            for (int j = 0; j < 4; j++)
                acc[i][j] = mfma16(af[i], bf[j], acc[i][j]);
    }

#pragma unroll
    for (int j = 0; j < 4; j++) {
        int col = n0 + wcol + j * 16 + l15;
        float bv = bias[col];
#pragma unroll
        for (int i = 0; i < 4; i++) {
#pragma unroll
            for (int r = 0; r < 4; r++) {
                int row = m0 + wrow + i * 16 + quad * 4 + r;
                C[(size_t)row * N + col] = acc[i][j][r] + bv;
            }
        }
    }
}

// ---------------- fused cosine attention v4: 128-q blocks, 2 waves x 64 q ----------------
// grid: (L/128, B*H), block 128 threads. 4 blocks/CU (LDS 32.5 KB, grid 1024).
// kf/vf fragment reads amortized over 64 q/wave; v3 inner loop, v2 occupancy.
__global__ __launch_bounds__(128) void attn_k(const _Float16* __restrict__ Q,
                                              const _Float16* __restrict__ K,
                                              const _Float16* __restrict__ VtG,
                                              _Float16* __restrict__ Mg) {
    __shared__ _Float16 Ks[64 * 64];   // 8 KB
    __shared__ _Float16 Vt[64 * 64];   // 8 KB
    __shared__ _Float16 Ps[128 * 64];  // 16 KB
    __shared__ float lsum[128];

    const float C2 = 20.60992915555662f;  // log2(e)/0.07
    const float OFF = 6.0f;

    int tid = threadIdx.x, wave = tid >> 6, lane = tid & 63;
    int quad = lane >> 4, l15 = lane & 15;
    int bh = blockIdx.y;
    int b = bh >> 4, h = bh & 15;
    int q0 = blockIdx.x * 128;
    size_t rowBase = (size_t)b * LL;
    int colBase = h * 64;
    int wq = wave * 64;   // wave owns queries wq..wq+63
    int sw = l15 & 7;

    // Q fragments in registers for the whole kernel: 4 ib x 2 ks
    half8 qf[4][2];
#pragma unroll
    for (int ib = 0; ib < 4; ib++)
#pragma unroll
        for (int ks = 0; ks < 2; ks++)
            qf[ib][ks] = *(const half8*)(Q + (rowBase + q0 + wq + ib * 16 + l15) * DD +
                                         colBase + ks * 32 + quad * 8);

    // staging: 512 16B-slots each for K and Vt over 128 threads -> 4 slots each
    const _Float16* kg[4];
    const _Float16* vg[4];
    char* kl[4];
    char* vl[4];
#pragma unroll
    for (int p = 0; p < 4; p++) {
        int s = p * 128 + tid;
        int r = s >> 3, cs = s & 7;
        int ck = cs ^ (r & 7);
        kg[p] = K + (rowBase + r) * DD + colBase + ck * 8;
        kl[p] = (char*)Ks + s * 16;
        vg[p] = VtG + ((size_t)bh * 64 + r) * LL + ck * 8;
        vl[p] = (char*)Vt + s * 16;
    }

    floatx4 oacc[4][4] = {};
    float fsum[4] = {0.f, 0.f, 0.f, 0.f};

    for (int kt = 0; kt < LL; kt += 64) {
        __syncthreads();
#pragma unroll
        for (int p = 0; p < 4; p++) {
            gload_lds16(kg[p], kl[p]); kg[p] += 64 * DD;
            gload_lds16(vg[p], vl[p]); vg[p] += 64;
        }
        __syncthreads();

        // ---- S^T = K * Q^T : 64 keys x 64 queries per wave ----
        floatx4 st[4][4] = {};  // [ib][jb(key block)]
#pragma unroll
        for (int ks = 0; ks < 2; ks++) {
            half8 kf[4];
#pragma unroll
            for (int jb = 0; jb < 4; jb++)
                kf[jb] = *(half8*)&Ks[(jb * 16 + l15) * 64 + (((ks * 4 + quad) ^ sw) * 8)];
#pragma unroll
            for (int ib = 0; ib < 4; ib++)
#pragma unroll
                for (int jb = 0; jb < 4; jb++)
                    st[ib][jb] = mfma16(kf[jb], qf[ib][ks], st[ib][jb]);
        }

        // ---- P = exp2(s*C2-OFF), pack -> b64 LDS writes (wave-exclusive rows) ----
#pragma unroll
        for (int ib = 0; ib < 4; ib++) {
#pragma unroll
            for (int jb = 0; jb < 4; jb++) {
                float e0 = __builtin_amdgcn_exp2f(st[ib][jb][0] * C2 - OFF);
                float e1 = __builtin_amdgcn_exp2f(st[ib][jb][1] * C2 - OFF);
                float e2 = __builtin_amdgcn_exp2f(st[ib][jb][2] * C2 - OFF);
                float e3 = __builtin_amdgcn_exp2f(st[ib][jb][3] * C2 - OFF);
                fsum[ib] += (e0 + e1) + (e2 + e3);
                half2 p01 = __builtin_bit_cast(half2, __builtin_amdgcn_cvt_pkrtz(e0, e1));
                half2 p23 = __builtin_bit_cast(half2, __builtin_amdgcn_cvt_pkrtz(e2, e3));
                half4 pk; pk[0] = p01[0]; pk[1] = p01[1]; pk[2] = p23[0]; pk[3] = p23[1];
                int chunk = (jb * 2 + (quad >> 1)) ^ sw;
                *(half4*)((char*)Ps + (wq + ib * 16 + l15) * 128 + chunk * 16 + (quad & 1) * 8) = pk;
            }
        }

        // ---- O += P * V^T-frags ----
#pragma unroll
        for (int kb = 0; kb < 2; kb++) {
            half8 pf[4], vf[4];
#pragma unroll
            for (int ib = 0; ib < 4; ib++)
                pf[ib] = *(half8*)&Ps[(wq + ib * 16 + l15) * 64 + (((kb * 4 + quad) ^ sw) * 8)];
#pragma unroll
            for (int jb = 0; jb < 4; jb++)
                vf[jb] = *(half8*)&Vt[(jb * 16 + l15) * 64 + (((kb * 4 + quad) ^ sw) * 8)];
#pragma unroll
            for (int ib = 0; ib < 4; ib++)
#pragma unroll
                for (int jb = 0; jb < 4; jb++)
                    oacc[ib][jb] = mfma16(pf[ib], vf[jb], oacc[ib][jb]);
        }
    }

    // ---- epilogue ----
#pragma unroll
    for (int ib = 0; ib < 4; ib++) {
        float v = fsum[ib];
        v += __shfl_xor(v, 16);
        v += __shfl_xor(v, 32);
        lsum[wq + ib * 16 + l15] = v;
    }
#pragma unroll
    for (int ib = 0; ib < 4; ib++) {
#pragma unroll
        for (int r = 0; r < 4; r++) {
            float inv = 1.0f / lsum[wq + ib * 16 + quad * 4 + r];
            int qrow = q0 + wq + ib * 16 + quad * 4 + r;
#pragma unroll
            for (int jb = 0; jb < 4; jb++) {
                float v = oacc[ib][jb][r] * inv;
                Mg[(rowBase + qrow) * DD + colBase + jb * 16 + l15] = (_Float16)v;
            }
        }
    }
}

// ---------------- launch ----------------
extern "C" void kernel_launch(void* const* d_in, const int* in_sizes, int n_in,
                              void* d_out, int out_size, void* d_ws, size_t ws_size,
                              hipStream_t stream) {
    (void)in_sizes; (void)n_in; (void)out_size; (void)ws_size;
    const float* q  = (const float*)d_in[0];
    const float* k  = (const float*)d_in[1];
    const float* v  = (const float*)d_in[2];
    const float* Wq = (const float*)d_in[3];
    const float* bq = (const float*)d_in[4];
    const float* Wk = (const float*)d_in[5];
    const float* bk = (const float*)d_in[6];
    const float* Wv = (const float*)d_in[7];
    const float* bv = (const float*)d_in[8];
    const float* Wo = (const float*)d_in[9];
    const float* bo = (const float*)d_in[10];

    const size_t NQKV = (size_t)MM * DD;  // 8388608
    const size_t NW = (size_t)DD * DD;    // 1048576

    _Float16* q16  = (_Float16*)d_ws;
    _Float16* wq16 = q16 + 3 * NQKV;
    _Float16* wk16 = wq16 + NW;
    _Float16* wv16 = wk16 + NW;
    _Float16* wo16 = wv16 + NW;
    _Float16* Qp   = wo16 + NW;
    _Float16* Kp   = Qp + NQKV;
    _Float16* VtG  = Kp + NQKV;
    _Float16* Mg   = VtG + NQKV;

    cvt_all<<<dim3(3 * 8192 + 4 * 1024), dim3(256), 0, stream>>>(q, k, v, Wq, Wk, Wv, Wo, q16);

    gemm_qkv<<<dim3(24, MM / 128), dim3(256), 0, stream>>>(q16, wq16, wk16, wv16,
                                                           bq, bk, bv, Qp, Kp, VtG);

    attn_k<<<dim3(LL / 128, BB * NH), dim3(128), 0, stream>>>(Qp, Kp, VtG, Mg);

    gemm_out<<<dim3(1024 / 128, MM / 128), dim3(256), 0, stream>>>(Mg, wo16, bo, (float*)d_out);
}